// Round 9
// baseline (195.025 us; speedup 1.0000x reference)
//
#include <hip/hip_runtime.h>
#include <hip/hip_bf16.h>
#include <stdint.h>
#include <stddef.h>

typedef __bf16 bf16_t;
typedef __attribute__((ext_vector_type(8))) __bf16 bf16x8;   // 4 VGPRs, MFMA A/B operand
typedef __attribute__((ext_vector_type(4))) __bf16 bf16x4;   // 8B packed P store
typedef __attribute__((ext_vector_type(4))) float f32x4;     // MFMA C/D

#define MFMA_BF16(a, b, c) __builtin_amdgcn_mfma_f32_16x16x32_bf16((a), (b), (c), 0, 0, 0)

// ---------------- fused prep: dtype-detect + cvt_x + both weight transposes -----
// Every block re-derives the dtype flag from the SAME fixed 8KB sample of x
// (identical data -> identical decision; no inter-block dependency). Block 0
// publishes it for the downstream kernels. Then flattened-blockIdx dispatch:
//   [0, 2048)        cvt_x block               (2,2048,1024) f32 -> bf16
//   [2048, 5120)     W_attn transpose 32x32    (1024,3072) -> Wat (3072,1024)
//   [5120, 6144)     W_proj transpose 32x32    (1024,1024) -> Wpt (1024,1024)
__global__ __launch_bounds__(256) void prep(const void* __restrict__ x,
                                            const void* __restrict__ Wa,
                                            const void* __restrict__ Wp,
                                            bf16_t* __restrict__ xb,
                                            bf16_t* __restrict__ Wat,
                                            bf16_t* __restrict__ Wpt,
                                            int* __restrict__ flag) {
  __shared__ int dcnt;
  __shared__ bf16_t tile[32][33];

  const int tid = threadIdx.x;
  if (tid == 0) dcnt = 0;
  __syncthreads();
  {
    const unsigned short* p = (const unsigned short*)x + tid * 16;
    int local = 0;
#pragma unroll
    for (int i = 0; i < 16; ++i) {
      const int e = (p[i] >> 7) & 0xFF;
      if (e >= 0x8D) local++;
    }
    if (local) atomicAdd(&dcnt, local);
  }
  __syncthreads();
  const int isF32 = (dcnt > 4) ? 1 : 0;

  const int b = blockIdx.x;
  if (b == 0 && tid == 0) *flag = isF32;

  if (b < 2048) {
    if (!isF32) return;  // already bf16; GEMM reads x directly
    const size_t i = ((size_t)b * 256 + tid) * 8;
    const float4 a0 = *(const float4*)((const float*)x + i);
    const float4 a1 = *(const float4*)((const float*)x + i + 4);
    bf16x8 r;
    r[0] = (__bf16)a0.x; r[1] = (__bf16)a0.y; r[2] = (__bf16)a0.z; r[3] = (__bf16)a0.w;
    r[4] = (__bf16)a1.x; r[5] = (__bf16)a1.y; r[6] = (__bf16)a1.z; r[7] = (__bf16)a1.w;
    *(bf16x8*)(xb + i) = r;
    return;
  }

  const void* in;
  bf16_t* out;
  int R, C, bx, by;
  if (b < 5120) {
    const int idx = b - 2048;
    in = Wa; out = Wat; R = 1024; C = 3072;
    bx = idx % 96; by = idx / 96;
  } else {
    const int idx = b - 5120;
    in = Wp; out = Wpt; R = 1024; C = 1024;
    bx = idx & 31; by = idx >> 5;
  }
  const int tx = tid & 31, ty = tid >> 5;
  const int r0 = by * 32, c0 = bx * 32;
#pragma unroll
  for (int i = 0; i < 4; ++i) {
    const size_t idx2 = (size_t)(r0 + ty + i * 8) * C + (c0 + tx);
    tile[ty + i * 8][tx] = isF32 ? (bf16_t)((const float*)in)[idx2]
                                 : ((const bf16_t*)in)[idx2];
  }
  __syncthreads();
#pragma unroll
  for (int i = 0; i < 4; ++i)
    out[(size_t)(c0 + ty + i * 8) * R + (r0 + tx)] = tile[tx][ty + i * 8];
}

// ---------------- GEMM: C = A * Bt^T + bias --------------------------------------
// Main loop = R4 version (known-good). 128x128 tile, BK=64, register-prefetch
// staging, padded LDS stride 72.
// MODE 1: Q/K blocks re-tile via LDS -> 16B stores to Qs (pre-scaled) / Kb;
//         V-blocks (n0>=2048) transpose tile via LDS -> 16B stores to Vt.
// MODE 2: A = head-major attn out in Qs (h = k0>>6 exact at BK=64); plain C store.
#define GP 72
template <int MODE>
__global__ __launch_bounds__(256) void gemm_bt(const void* A0,
                        const bf16_t* __restrict__ xb,
                        const bf16_t* __restrict__ Bt,
                        const void* __restrict__ bias,
                        void* C,
                        bf16_t* __restrict__ Qs,
                        bf16_t* __restrict__ Kb,
                        bf16_t* __restrict__ dout_bf,
                        int M, int N, int K,
                        const int* __restrict__ flagp) {
  const int isF32 = *flagp;
  const bf16_t* A = (MODE == 1 && isF32) ? xb : (const bf16_t*)A0;
  bf16_t* Vt = dout_bf + (isF32 ? (size_t)4194304 : 0);  // d_out hi half if f32 out

  __shared__ __align__(16) unsigned char pool[128 * GP * 2 * 2];
  bf16_t* As = (bf16_t*)pool;
  bf16_t* Bs = (bf16_t*)pool + 128 * GP;

  const int tid = threadIdx.x;
  const int w = tid >> 6, lane = tid & 63;
  const int quad = lane >> 4, l16 = lane & 15;
  const int wm = w >> 1, wn = w & 1;
  const int m0 = blockIdx.y * 128, n0 = blockIdx.x * 128;

  auto loadA = [&](int k0, int it) -> bf16x8 {
    const int g = it * 256 + tid;
    const int row = g >> 3, col = (g & 7) * 8;
    const int m = m0 + row;
    if (MODE == 2) {
      const size_t aoff =
          ((size_t)((m >> 11) * 16 + (k0 >> 6)) * 2048 + (m & 2047)) * 64 + col;
      return *(const bf16x8*)(A + aoff);
    }
    return *(const bf16x8*)(A + (size_t)m * K + (k0 + col));
  };
  auto loadB = [&](int k0, int it) -> bf16x8 {
    const int g = it * 256 + tid;
    const int row = g >> 3, col = (g & 7) * 8;
    return *(const bf16x8*)(Bt + (size_t)(n0 + row) * K + (k0 + col));
  };

  f32x4 acc[4][4];
#pragma unroll
  for (int i = 0; i < 4; ++i)
#pragma unroll
    for (int j = 0; j < 4; ++j) acc[i][j] = f32x4{0.f, 0.f, 0.f, 0.f};

  bf16x8 va[4], vb[4];
#pragma unroll
  for (int it = 0; it < 4; ++it) { va[it] = loadA(0, it); vb[it] = loadB(0, it); }

  for (int k0 = 0; k0 < K; k0 += 64) {
    __syncthreads();
#pragma unroll
    for (int it = 0; it < 4; ++it) {
      const int g = it * 256 + tid;
      const int row = g >> 3, col = (g & 7) * 8;
      *(bf16x8*)&As[row * GP + col] = va[it];
      *(bf16x8*)&Bs[row * GP + col] = vb[it];
    }
    __syncthreads();

    if (k0 + 64 < K) {
#pragma unroll
      for (int it = 0; it < 4; ++it) { va[it] = loadA(k0 + 64, it); vb[it] = loadB(k0 + 64, it); }
    }

#pragma unroll
    for (int kc = 0; kc < 2; ++kc) {
      bf16x8 af[4], bfr[4];
#pragma unroll
      for (int i = 0; i < 4; ++i)
        af[i] = *(const bf16x8*)&As[(wm * 64 + i * 16 + l16) * GP + kc * 32 + quad * 8];
#pragma unroll
      for (int j = 0; j < 4; ++j)
        bfr[j] = *(const bf16x8*)&Bs[(wn * 64 + j * 16 + l16) * GP + kc * 32 + quad * 8];
#pragma unroll
      for (int i = 0; i < 4; ++i)
#pragma unroll
        for (int j = 0; j < 4; ++j) acc[i][j] = MFMA_BF16(af[i], bfr[j], acc[i][j]);
    }
  }

  // ---------------- epilogue — C/D layout: row = quad*4 + r, col = l16 ----------
  if (MODE == 1 && n0 >= 2048) {
    // V blocks: transpose tile via LDS, then coalesced 16B stores to Vt (B,H,D,S).
    bf16_t* tp = (bf16_t*)pool;  // [n_local][m_local], stride 136
    __syncthreads();
#pragma unroll
    for (int j = 0; j < 4; ++j) {
      const int n_l = wn * 64 + j * 16 + l16;
      const int n = n0 + n_l;
      const float bj = isF32 ? ((const float*)bias)[n] : (float)((const bf16_t*)bias)[n];
#pragma unroll
      for (int i = 0; i < 4; ++i) {
#pragma unroll
        for (int r = 0; r < 4; ++r) {
          const int m_l = wm * 64 + i * 16 + quad * 4 + r;
          tp[n_l * 136 + m_l] = (bf16_t)(acc[i][j][r] + bj);
        }
      }
    }
    __syncthreads();
    const int b = m0 >> 11, s0 = m0 & 2047;
#pragma unroll
    for (int seg = 0; seg < 8; ++seg) {
      const int idx = seg * 256 + tid;
      const int n_l = idx >> 4, ms = (idx & 15) * 8;
      const bf16x8 v8 = *(const bf16x8*)&tp[n_l * 136 + ms];
      const int e = (n0 + n_l) & 1023, h = e >> 6, d = e & 63;
      *(bf16x8*)(Vt + ((size_t)(b * 16 + h) * 64 + d) * 2048 + s0 + ms) = v8;
    }
    return;
  }

  if (MODE == 1) {
    // Q/K blocks: re-tile [m_l][n_l] via LDS -> coalesced 16B stores.
    bf16_t* tp = (bf16_t*)pool;  // [m_local][n_local], stride 136
    __syncthreads();
    const bool isQ = (n0 < 1024);
    const float sc = isQ ? 0.18033688011f : 1.0f;  // Q pre-scale: 1/8 * log2(e)
#pragma unroll
    for (int j = 0; j < 4; ++j) {
      const int n_l = wn * 64 + j * 16 + l16;
      const int n = n0 + n_l;
      const float bj = isF32 ? ((const float*)bias)[n] : (float)((const bf16_t*)bias)[n];
#pragma unroll
      for (int i = 0; i < 4; ++i) {
#pragma unroll
        for (int r = 0; r < 4; ++r) {
          const int m_l = wm * 64 + i * 16 + quad * 4 + r;
          tp[m_l * 136 + n_l] = (bf16_t)((acc[i][j][r] + bj) * sc);
        }
      }
    }
    __syncthreads();
    bf16_t* dst = isQ ? Qs : Kb;
#pragma unroll
    for (int seg = 0; seg < 8; ++seg) {
      const int idx = seg * 256 + tid;
      const int m_l = idx >> 4, ns = (idx & 15) * 8;
      const bf16x8 v8 = *(const bf16x8*)&tp[m_l * 136 + ns];
      const int m = m0 + m_l;
      const int e = (n0 + ns) & 1023, h = e >> 6, d = e & 63;
      const int bb = m >> 11, s = m & 2047;
      *(bf16x8*)(dst + (((size_t)(bb * 16 + h) * 2048 + s) * 64 + d)) = v8;
    }
    return;
  }

#pragma unroll
  for (int j = 0; j < 4; ++j) {
    const int n = n0 + wn * 64 + j * 16 + l16;
    const float bj = isF32 ? ((const float*)bias)[n] : (float)((const bf16_t*)bias)[n];
#pragma unroll
    for (int i = 0; i < 4; ++i) {
      const int mbase = m0 + wm * 64 + i * 16 + quad * 4;
#pragma unroll
      for (int r = 0; r < 4; ++r) {
        const int m = mbase + r;
        const float v = acc[i][j][r] + bj;
        if (isF32) ((float*)C)[(size_t)m * N + n] = v;
        else       ((bf16_t*)C)[(size_t)m * N + n] = (bf16_t)v;
      }
    }
  }
}

// ---------------- causal flash attention -----------------------------------------
// v8 = v2.1 inner loop (proven correct in R2: 32 q-rows/wave, K-frags hoisted
// once for 2 q-groups, packed 8B P stores, fixed diagonal guard) + v4's
// balanced-decode grid idea:
//   512 blocks; g=bid>>5 in [0..16), bh=bid&31; qt = g<8 ? 15-g : g-8.
//   Stride-256 residue class {g, g+8} -> per-CU work = (2(15-g)+2)+(2g+2) = 36
//   tile-iters CONSTANT; longest first; CU's two blocks share bh (K/V L2 reuse).
// LDS instr per q-row: 1.0 (v4: 1.625) -> attacks the measured LDS-pipe roofline.
// LDS 36.9KB -> 2 blocks/CU resident = 16 waves/CU (same as v4).
#define AP 72
#define PSP 72
__global__ __launch_bounds__(256, 2) void attn_kernel(bf16_t* QO,
                                                      const bf16_t* __restrict__ Kb,
                                                      const bf16_t* __restrict__ dout_bf,
                                                      const int* __restrict__ flagp) {
  const int isF32 = *flagp;
  const bf16_t* Vt = dout_bf + (isF32 ? (size_t)4194304 : 0);

  __shared__ __align__(16) bf16_t Ks[64 * AP];      // [key][d]
  __shared__ __align__(16) bf16_t Vs[64 * AP];      // [d][key]
  __shared__ __align__(16) bf16_t Ps[4][32 * PSP];  // per-wave P [q_local][key]

  const int bid = blockIdx.x;
  const int g2 = bid >> 5, bh = bid & 31;
  const int qt = (g2 < 8) ? (15 - g2) : (g2 - 8);   // balanced + longest-first

  const int tid = threadIdx.x, w = tid >> 6, lane = tid & 63;
  const int quad = lane >> 4, l16 = lane & 15;

  bf16_t* Q = QO + (size_t)bh * 2048 * 64;
  const bf16_t* K = Kb + (size_t)bh * 2048 * 64;
  const bf16_t* V = Vt + (size_t)bh * 64 * 2048;

  const int qrow = qt * 128 + w * 32;               // this wave's 32 q-rows
  const int nkt = 2 * qt + 2;                       // causal 64-key tiles (block)

  // Q fragments for both 16-row groups (B-operand of swapped QK: cols = q)
  bf16x8 qf[2][2];
#pragma unroll
  for (int g = 0; g < 2; ++g)
#pragma unroll
    for (int kk = 0; kk < 2; ++kk)
      qf[g][kk] = *(const bf16x8*)(Q + (size_t)(qrow + g * 16 + l16) * 64 + kk * 32 + quad * 8);

  f32x4 oacc[2][4];
  float lsum[2] = {0.f, 0.f};
#pragma unroll
  for (int g = 0; g < 2; ++g)
#pragma unroll
    for (int jd = 0; jd < 4; ++jd) oacc[g][jd] = f32x4{0.f, 0.f, 0.f, 0.f};

  const int srow8 = lane >> 3;         // 0..7
  const int scol8 = (lane & 7) * 8;    // 0..56

  auto loadK = [&](int kt, int it) -> bf16x8 {
    const int row = (w + it * 4) * 8 + srow8;
    return *(const bf16x8*)(K + (size_t)(kt * 64 + row) * 64 + scol8);
  };
  auto loadV = [&](int kt, int it) -> bf16x8 {
    const int row = (w + it * 4) * 8 + srow8;
    return *(const bf16x8*)(V + (size_t)row * 2048 + kt * 64 + scol8);
  };

  bf16x8 kv[2], vv[2];
#pragma unroll
  for (int it = 0; it < 2; ++it) { kv[it] = loadK(0, it); vv[it] = loadV(0, it); }

  for (int kt = 0; kt < nkt; ++kt) {
    __syncthreads();  // prev iter's Ks/Vs fragment reads done
#pragma unroll
    for (int it = 0; it < 2; ++it) {
      const int row = (w + it * 4) * 8 + srow8;
      *(bf16x8*)&Ks[row * AP + scol8] = kv[it];  // Ks[key][d]
      *(bf16x8*)&Vs[row * AP + scol8] = vv[it];  // Vs[d][key]
    }
    __syncthreads();

    // prefetch next tile; stays in flight through QK/softmax/PV
    if (kt + 1 < nkt) {
#pragma unroll
      for (int it = 0; it < 2; ++it) { kv[it] = loadK(kt + 1, it); vv[it] = loadV(kt + 1, it); }
    }

    const int kbase = kt * 64;
    const bool active = kbase <= qrow + 31;  // wave-uniform: any unmasked key?
    if (active) {
      // hoist K fragments once; reused by both q-groups (A-operand rows = key)
      bf16x8 kf[4][2];
#pragma unroll
      for (int j = 0; j < 4; ++j) {
        kf[j][0] = *(const bf16x8*)&Ks[(j * 16 + l16) * AP + quad * 8];
        kf[j][1] = *(const bf16x8*)&Ks[(j * 16 + l16) * AP + 32 + quad * 8];
      }

#pragma unroll
      for (int g = 0; g < 2; ++g) {
        const int qg = qrow + g * 16 + l16;        // this lane's q (column index)
        if (kbase > qrow + g * 16 + 15) continue;  // group fully masked

        // swapped S = K Q^T: row = key (quad*4+r within j*16), col = q (l16)
        f32x4 s[4];
#pragma unroll
        for (int j = 0; j < 4; ++j) {
          f32x4 z = f32x4{0.f, 0.f, 0.f, 0.f};
          z = MFMA_BF16(kf[j][0], qf[g][0], z);
          s[j] = MFMA_BF16(kf[j][1], qf[g][1], z);
        }

        if (kbase + 63 > qrow + g * 16) {  // diagonal: tile max key > group min q
#pragma unroll
          for (int j = 0; j < 4; ++j) {
            const int key = kbase + j * 16 + quad * 4;
#pragma unroll
            for (int r = 0; r < 4; ++r)
              if (key + r > qg) s[j][r] = -1e30f;
          }
        }

        // no-max softmax: p = exp2(s); lane-local partial of l (one q per lane);
        // 4 consecutive keys per reg quad -> one packed 8B store per j
        float ls = 0.f;
#pragma unroll
        for (int j = 0; j < 4; ++j) {
          bf16x4 pk;
#pragma unroll
          for (int r = 0; r < 4; ++r) {
            const float p = exp2f(s[j][r]);
            ls += p;
            pk[r] = (__bf16)p;
          }
          *(bf16x4*)&Ps[w][(g * 16 + l16) * PSP + j * 16 + quad * 4] = pk;
        }
        lsum[g] += ls;
      }

      // PV: V fragments shared across both q-groups (same-wave RAW on Ps)
#pragma unroll
      for (int kk = 0; kk < 2; ++kk) {
        bf16x8 vf[4];
#pragma unroll
        for (int jd = 0; jd < 4; ++jd)
          vf[jd] = *(const bf16x8*)&Vs[(jd * 16 + l16) * AP + kk * 32 + quad * 8];
#pragma unroll
        for (int g = 0; g < 2; ++g) {
          if (kbase > qrow + g * 16 + 15) continue;
          const bf16x8 pf = *(const bf16x8*)&Ps[w][(g * 16 + l16) * PSP + kk * 32 + quad * 8];
#pragma unroll
          for (int jd = 0; jd < 4; ++jd) oacc[g][jd] = MFMA_BF16(pf, vf[jd], oacc[g][jd]);
        }
      }
    }
  }

  // l reduction: partials for q=(g,l16) live in lanes {l16, l16+16, l16+32, l16+48}
#pragma unroll
  for (int g = 0; g < 2; ++g) {
    lsum[g] += __shfl_xor(lsum[g], 16);
    lsum[g] += __shfl_xor(lsum[g], 32);
  }

  // O /= l, write in place over this wave's own Q rows (private -> race-free)
#pragma unroll
  for (int g = 0; g < 2; ++g) {
#pragma unroll
    for (int r = 0; r < 4; ++r) {
      const float lr = fmaxf(__shfl(lsum[g], quad * 4 + r, 16), 1e-30f);
      const int q = qrow + g * 16 + quad * 4 + r;
#pragma unroll
      for (int jd = 0; jd < 4; ++jd) {
        const int d = jd * 16 + l16;
        Q[(size_t)q * 64 + d] = (bf16_t)(oacc[g][jd][r] / lr);
      }
    }
  }
}

// ---------------- launch ----------------------------------------------------------
extern "C" void kernel_launch(void* const* d_in, const int* in_sizes, int n_in,
                              void* d_out, int out_size, void* d_ws, size_t ws_size,
                              hipStream_t stream) {
  const void* x      = d_in[0];   // (2,2048,1024)
  const void* W_attn = d_in[1];   // (1024,3072)
  const void* b_attn = d_in[2];   // (3072,)
  const void* W_proj = d_in[3];   // (1024,1024)
  const void* b_proj = d_in[4];   // (1024,)

  // ws: flag + Qs 8MB + Kb 8MB + Wat 6MB + Wpt 2MB = 24MB.
  // d_out (16MB when f32 out): lo half = xb (bf16 x), hi half = Vt; both dead
  // before proj GEMM overwrites d_out. (bf16 out: xb unused, Vt = lo half.)
  char* ws = (char*)d_ws;
  size_t off = 0;
  auto alloc = [&](size_t bytes) {
    char* p = ws + off;
    off += (bytes + 255) & ~(size_t)255;
    return p;
  };
  int*    flag = (int*)alloc(256);
  bf16_t* Qs   = (bf16_t*)alloc((size_t)32 * 2048 * 64 * 2);   // Q, then O in place
  bf16_t* Kb   = (bf16_t*)alloc((size_t)32 * 2048 * 64 * 2);
  bf16_t* Wat  = (bf16_t*)alloc((size_t)3072 * 1024 * 2);      // W_attn^T (N,K) bf16
  bf16_t* Wpt  = (bf16_t*)alloc((size_t)1024 * 1024 * 2);      // W_proj^T bf16
  bf16_t* dout_bf = (bf16_t*)d_out;

  // 1 launch: detect + cvt_x + both transposes
  prep<<<dim3(6144), 256, 0, stream>>>(x, W_attn, W_proj, dout_bf, Wat, Wpt, flag);

  gemm_bt<1><<<dim3(3072 / 128, 4096 / 128), 256, 0, stream>>>(
      x, dout_bf, Wat, b_attn, nullptr, Qs, Kb, dout_bf, 4096, 3072, 1024, flag);

  attn_kernel<<<dim3(512), 256, 0, stream>>>(Qs, Kb, dout_bf, flag);

  gemm_bt<2><<<dim3(1024 / 128, 4096 / 128), 256, 0, stream>>>(
      Qs, nullptr, Wpt, b_proj, d_out, nullptr, nullptr, dout_bf, 4096, 1024, 1024, flag);
}